// Round 8
// baseline (684.213 us; speedup 1.0000x reference)
//
#include <hip/hip_runtime.h>

typedef _Float16 f16;
typedef _Float16 f16x8 __attribute__((ext_vector_type(8)));
typedef _Float16 f16x4 __attribute__((ext_vector_type(4)));
typedef float f32x4 __attribute__((ext_vector_type(4)));

#define MFMA16(a, b, c) __builtin_amdgcn_mfma_f32_16x16x32_f16((a), (b), (c), 0, 0, 0)
#define CLAMP01(x) __builtin_amdgcn_fmed3f((x), 0.0f, 1.0f)

constexpr int BATCH = 16384;
constexpr int H     = 256;
constexpr int IN    = 784;
constexpr int OUT   = 10;
constexpr int TSTEP = 50;
constexpr int BM    = 32;    // 2 m-tiles of 16
constexpr int NTHR  = 512;   // 8 waves: 0-3 GEMM1 (64h each), 4-7 GEMM2 (64h each)
constexpr int SROW  = 264;   // padded f16 row stride (33 quads, conflict-free b128)
constexpr int S0ROW = 40;    // f16 row stride for s0 tile (K padded 10->32)
constexpr int DROW  = 808;   // data staging stride (101 quads, odd)

// f16-unit LDS offsets
constexpr int OFF_S1  = 0;                       // [32][264] = 8448
constexpr int OFF_S2  = OFF_S1 + BM * SROW;      // 8448
constexpr int OFF_S0  = OFF_S2 + BM * SROW;      // 16896  f16 s0 [32][40]
constexpr int OFF_W0N = OFF_S0 + BM * S0ROW;     // 18176  W0 natural [16][264]
constexpr int OFF_S0F = OFF_W0N + 16 * SROW;     // 22400  f32 s0 master [32][16] = 1024 f16
constexpr int POOL_F16 = BM * SROW * 4;          // 33792 f16 = 67.6 KB (epilogue [32][264] f32)
// Staging overlay [16][808]=12928 f16 in [0,12928) -> only touches S1 + part of S2.

__global__ __launch_bounds__(NTHR, 2) void ep_step_kernel(
    const float* __restrict__ data, const float* __restrict__ s0_in,
    const float* __restrict__ s1_in, const float* __restrict__ s2_in,
    const float* __restrict__ W0, const float* __restrict__ b0,
    const float* __restrict__ W2, const float* __restrict__ b2,
    const float* __restrict__ W4, const float* __restrict__ b4,
    float* __restrict__ out)
{
    __shared__ __align__(16) f16 pool[POOL_F16];
    float* const s0F = (float*)&pool[OFF_S0F];   // [32][16] f32 master s0

    const int tid  = threadIdx.x;
    const int wave = tid >> 6;
    const int lane = tid & 63;
    const int q    = lane >> 4;
    const int l16  = lane & 15;
    const int m0   = blockIdx.x * BM;
    const int role = (wave < 4) ? 0 : 1;   // 0: produce s1 (read s2,s0); 1: produce s2 (read s1)
    const int h0   = (wave & 3) * 64;      // 64-h slab -> 4 h-tiles of 16
    const bool doS0 = (wave == 4);         // also computes o0 / owns s0

    // ---- phase 1a: W0N tile, s0 f16 tile from s0_in (o>=10 zero), s0F master ----------------
    for (int i = tid; i < 16 * SROW; i += NTHR) {
        int o = i / SROW, k = i % SROW;
        pool[OFF_W0N + i] = (o < OUT && k < H) ? (f16)W0[o * H + k] : (f16)0.f;
    }
    for (int i = tid; i < BM * S0ROW; i += NTHR) {
        int m = i / S0ROW, o = i % S0ROW;
        pool[OFF_S0 + i] = (o < OUT) ? (f16)s0_in[(size_t)(m0 + m) * OUT + o] : (f16)0.f;
    }
    for (int i = tid; i < BM * 16; i += NTHR) {
        int m = i >> 4, o = i & 15;
        s0F[i] = (o < OUT) ? s0_in[(size_t)(m0 + m) * OUT + o] : 0.f;
    }

    // ---- phase 1b: persistent weight fragments (64h slab; role-dependent orientation) --------
    f16x8 wf[4][8];
    if (role == 0) {  // wB: A'[h][k] = W2[h][k]
        #pragma unroll
        for (int ht = 0; ht < 4; ++ht) {
            int h = h0 + ht * 16 + l16;
            #pragma unroll
            for (int kk = 0; kk < 8; ++kk) {
                int kb = kk * 32 + q * 8;
                f32x4 u0 = *(const f32x4*)(W2 + h * H + kb);
                f32x4 u1 = *(const f32x4*)(W2 + h * H + kb + 4);
                f16x8 wb;
                #pragma unroll
                for (int j = 0; j < 4; ++j) { wb[j] = (f16)u0[j]; wb[j + 4] = (f16)u1[j]; }
                wf[ht][kk] = wb;
            }
        }
    } else {          // wA: A'[h][k] = W2[k][h]
        #pragma unroll
        for (int ht = 0; ht < 4; ++ht) {
            int h = h0 + ht * 16 + l16;
            #pragma unroll
            for (int kk = 0; kk < 8; ++kk) {
                int kb = kk * 32 + q * 8;
                f16x8 wa;
                #pragma unroll
                for (int j = 0; j < 8; ++j) wa[j] = (f16)W2[(kb + j) * H + h];
                wf[ht][kk] = wa;
            }
        }
    }
    f16x8 w0c[4];     // role 0 only: A'[h][o] = W0[o][h], K padded 10->32
    if (role == 0) {
        #pragma unroll
        for (int ht = 0; ht < 4; ++ht) {
            int h = h0 + ht * 16 + l16;
            #pragma unroll
            for (int j = 0; j < 8; ++j) {
                int o = q * 8 + j;
                w0c[ht][j] = (o < OUT) ? (f16)W0[o * H + h] : (f16)0.f;
            }
        }
    }

    // ---- phase 2: staged data + x2 GEMM per m-tile (GEMM2 waves compute their 64h slab) ------
    f32x4 bx[2][4];   // role 0: bx[0][ht] = 0.5*b2 ; role 1: bx[mt][ht] = 0.5*(x2+b4)
    #pragma unroll 1
    for (int mt = 0; mt < 2; ++mt) {
        __syncthreads();   // staging region free (phase-1a / previous x2 readers done)
        for (int i = tid; i < 16 * (DROW / 4); i += NTHR) {
            int m  = i / (DROW / 4);
            int k4 = (i % (DROW / 4)) * 4;
            f16x4 p = {(f16)0.f, (f16)0.f, (f16)0.f, (f16)0.f};
            if (k4 < IN) {
                f32x4 v = *(const f32x4*)(data + (size_t)(m0 + mt * 16 + m) * IN + k4);
                #pragma unroll
                for (int j = 0; j < 4; ++j) p[j] = (f16)CLAMP01(v[j]);
            }
            *(f16x4*)&pool[m * DROW + k4] = p;
        }
        __syncthreads();
        if (role == 1) {
            f32x4 x2a[4] = {{0.f,0.f,0.f,0.f},{0.f,0.f,0.f,0.f},{0.f,0.f,0.f,0.f},{0.f,0.f,0.f,0.f}};
            for (int kk = 0; kk < 25; ++kk) {
                int kb = kk * 32 + q * 8;
                f16x8 bd = *(const f16x8*)&pool[l16 * DROW + kb];
                #pragma unroll
                for (int ht = 0; ht < 4; ++ht) {
                    int h = h0 + ht * 16 + l16;
                    f16x8 wa4;
                    if (kk < 24) {
                        f32x4 u0 = *(const f32x4*)(W4 + (size_t)h * IN + kb);
                        f32x4 u1 = *(const f32x4*)(W4 + (size_t)h * IN + kb + 4);
                        #pragma unroll
                        for (int j = 0; j < 4; ++j) { wa4[j] = (f16)u0[j]; wa4[j + 4] = (f16)u1[j]; }
                    } else {
                        #pragma unroll
                        for (int j = 0; j < 8; ++j) {
                            int k = kb + j;
                            wa4[j] = (k < IN) ? (f16)W4[(size_t)h * IN + k] : (f16)0.f;
                        }
                    }
                    x2a[ht] = MFMA16(wa4, bd, x2a[ht]);
                }
            }
            #pragma unroll
            for (int ht = 0; ht < 4; ++ht)
                #pragma unroll
                for (int r = 0; r < 4; ++r)
                    bx[mt][ht][r] = 0.5f * (x2a[ht][r] + b4[h0 + ht * 16 + q * 4 + r]);
        }
    }
    if (role == 0) {
        #pragma unroll
        for (int ht = 0; ht < 4; ++ht)
            #pragma unroll
            for (int r = 0; r < 4; ++r)
                bx[0][ht][r] = 0.5f * b2[h0 + ht * 16 + q * 4 + r];
    }
    f32x4 b0h = {0.f, 0.f, 0.f, 0.f};
    if (doS0) {
        #pragma unroll
        for (int r = 0; r < 4; ++r) {
            int o = q * 4 + r;
            if (o < OUT) b0h[r] = 0.5f * b0[o];
        }
    }

    // ---- master state for the owned slab (C layout) -------------------------------------------
    f32x4 sm[2][4];
    {
        const float* sin_ = role ? s2_in : s1_in;
        #pragma unroll
        for (int mt = 0; mt < 2; ++mt)
            #pragma unroll
            for (int ht = 0; ht < 4; ++ht)
                #pragma unroll
                for (int r = 0; r < 4; ++r)
                    sm[mt][ht][r] = sin_[(size_t)(m0 + mt * 16 + l16) * H + h0 + ht * 16 + q * 4 + r];
    }

    __syncthreads();  // x2 staging reads done; S1/S2 free for state
    // initial f16 state writeback (conflict-free b64)
    {
        f16* ws = &pool[role ? OFF_S2 : OFF_S1];
        #pragma unroll
        for (int mt = 0; mt < 2; ++mt)
            #pragma unroll
            for (int ht = 0; ht < 4; ++ht) {
                f16x4 pk;
                #pragma unroll
                for (int r = 0; r < 4; ++r) pk[r] = (f16)sm[mt][ht][r];
                *(f16x4*)&ws[(mt * 16 + l16) * SROW + h0 + ht * 16 + q * 4] = pk;
            }
    }
    __syncthreads();

    // ---- main loop ----------------------------------------------------------------------------
    #pragma unroll 1
    for (int t = 0; t < TSTEP; ++t) {
        if (role == 0) {
            // o1 = (s2 @ W2^T + s0 @ W0)^T for 64h x 32m
            f32x4 o1[2][4] = {};
            #pragma unroll
            for (int mt = 0; mt < 2; ++mt) {
                int mrow = mt * 16 + l16;
                #pragma unroll
                for (int kk = 0; kk < 8; ++kk) {
                    f16x8 bs2 = *(const f16x8*)&pool[OFF_S2 + mrow * SROW + kk * 32 + q * 8];
                    #pragma unroll
                    for (int ht = 0; ht < 4; ++ht)
                        o1[mt][ht] = MFMA16(wf[ht][kk], bs2, o1[mt][ht]);
                }
                f16x8 bs0 = *(const f16x8*)&pool[OFF_S0 + mrow * S0ROW + q * 8];
                #pragma unroll
                for (int ht = 0; ht < 4; ++ht)
                    o1[mt][ht] = MFMA16(w0c[ht], bs0, o1[mt][ht]);
            }
            __syncthreads();
            #pragma unroll
            for (int mt = 0; mt < 2; ++mt)
                #pragma unroll
                for (int ht = 0; ht < 4; ++ht) {
                    f16x4 pk;
                    #pragma unroll
                    for (int r = 0; r < 4; ++r) {
                        sm[mt][ht][r] = CLAMP01(fmaf(0.5f, sm[mt][ht][r],
                                                 fmaf(0.5f, o1[mt][ht][r], bx[0][ht][r])));
                        pk[r] = (f16)sm[mt][ht][r];
                    }
                    *(f16x4*)&pool[OFF_S1 + (mt * 16 + l16) * SROW + h0 + ht * 16 + q * 4] = pk;
                }
        } else {
            // o2 = (s1 @ W2)^T for 64h x 32m ; wave4 also o0 = (s1 @ W0^T)^T
            f32x4 o2[2][4] = {};
            f32x4 o0[2] = {{0.f,0.f,0.f,0.f},{0.f,0.f,0.f,0.f}};
            #pragma unroll
            for (int kk = 0; kk < 8; ++kk) {
                int kb = kk * 32 + q * 8;
                f16x8 a0;
                if (doS0) a0 = *(const f16x8*)&pool[OFF_W0N + l16 * SROW + kb];
                #pragma unroll
                for (int mt = 0; mt < 2; ++mt) {
                    f16x8 bs1 = *(const f16x8*)&pool[OFF_S1 + (mt * 16 + l16) * SROW + kb];
                    #pragma unroll
                    for (int ht = 0; ht < 4; ++ht)
                        o2[mt][ht] = MFMA16(wf[ht][kk], bs1, o2[mt][ht]);
                    if (doS0) o0[mt] = MFMA16(a0, bs1, o0[mt]);
                }
            }
            __syncthreads();
            #pragma unroll
            for (int mt = 0; mt < 2; ++mt)
                #pragma unroll
                for (int ht = 0; ht < 4; ++ht) {
                    f16x4 pk;
                    #pragma unroll
                    for (int r = 0; r < 4; ++r) {
                        sm[mt][ht][r] = CLAMP01(fmaf(0.5f, sm[mt][ht][r],
                                                 fmaf(0.5f, o2[mt][ht][r], bx[mt][ht][r])));
                        pk[r] = (f16)sm[mt][ht][r];
                    }
                    *(f16x4*)&pool[OFF_S2 + (mt * 16 + l16) * SROW + h0 + ht * 16 + q * 4] = pk;
                }
            if (doS0) {
                #pragma unroll
                for (int mt = 0; mt < 2; ++mt) {
                    int mrow = mt * 16 + l16;
                    f32x4 old = *(const f32x4*)&s0F[mrow * 16 + q * 4];
                    f32x4 nv;
                    f16x4 pk;
                    #pragma unroll
                    for (int r = 0; r < 4; ++r) {
                        nv[r] = CLAMP01(fmaf(0.5f, old[r], fmaf(0.5f, o0[mt][r], b0h[r])));
                        pk[r] = (f16)nv[r];
                    }
                    *(f32x4*)&s0F[mrow * 16 + q * 4] = nv;
                    *(f16x4*)&pool[OFF_S0 + mrow * S0ROW + q * 4] = pk;
                }
            }
        }
        __syncthreads();
    }

    // ---- epilogue -----------------------------------------------------------------------------
    f32x4 s0out[2];
    if (doS0) {
        #pragma unroll
        for (int mt = 0; mt < 2; ++mt)
            s0out[mt] = *(const f32x4*)&s0F[(mt * 16 + l16) * 16 + q * 4];
    }
    __syncthreads();  // s0F reads done before xf overlays it
    if (doS0) {
        #pragma unroll
        for (int mt = 0; mt < 2; ++mt)
            #pragma unroll
            for (int r = 0; r < 4; ++r) {
                int o = q * 4 + r;
                if (o < OUT) out[(size_t)(m0 + mt * 16 + l16) * OUT + o] = s0out[mt][r];
            }
    }
    float* xf = (float*)pool;  // [32][264] f32
    float* o1p = out + (size_t)BATCH * OUT;
    float* o2p = o1p + (size_t)BATCH * H;
    if (role == 0) {
        #pragma unroll
        for (int mt = 0; mt < 2; ++mt)
            #pragma unroll
            for (int ht = 0; ht < 4; ++ht)
                *(f32x4*)&xf[(mt * 16 + l16) * 264 + h0 + ht * 16 + q * 4] = sm[mt][ht];
    }
    __syncthreads();
    for (int i = tid; i < BM * H / 4; i += NTHR) {
        int m = i >> 6, c = (i & 63) * 4;
        f32x4 v = *(const f32x4*)&xf[m * 264 + c];
        *(f32x4*)&o1p[(size_t)(m0 + m) * H + c] = v;
    }
    __syncthreads();
    if (role == 1) {
        #pragma unroll
        for (int mt = 0; mt < 2; ++mt)
            #pragma unroll
            for (int ht = 0; ht < 4; ++ht)
                *(f32x4*)&xf[(mt * 16 + l16) * 264 + h0 + ht * 16 + q * 4] = sm[mt][ht];
    }
    __syncthreads();
    for (int i = tid; i < BM * H / 4; i += NTHR) {
        int m = i >> 6, c = (i & 63) * 4;
        f32x4 v = *(const f32x4*)&xf[m * 264 + c];
        *(f32x4*)&o2p[(size_t)(m0 + m) * H + c] = v;
    }
}

extern "C" void kernel_launch(void* const* d_in, const int* in_sizes, int n_in,
                              void* d_out, int out_size, void* d_ws, size_t ws_size,
                              hipStream_t stream) {
    const float* data  = (const float*)d_in[0];
    const float* s0_in = (const float*)d_in[1];
    const float* s1_in = (const float*)d_in[2];
    const float* s2_in = (const float*)d_in[3];
    const float* W0    = (const float*)d_in[4];
    const float* b0    = (const float*)d_in[5];
    const float* W2    = (const float*)d_in[6];
    const float* b2    = (const float*)d_in[7];
    const float* W4    = (const float*)d_in[8];
    const float* b4    = (const float*)d_in[9];
    float* out = (float*)d_out;

    ep_step_kernel<<<BATCH / BM, NTHR, 0, stream>>>(
        data, s0_in, s1_in, s2_in, W0, b0, W2, b2, W4, b4, out);
}